// Round 1
// baseline (111.569 us; speedup 1.0000x reference)
//
#include <hip/hip_runtime.h>
#include <math.h>

#define NA    180
#define HB    9             // band height in v
#define KB    29            // bands cover v in [-2, 259)
#define P0C   261           // u texels: u = -2..258
#define P0R   273           // rows: pv = v+4 (both P0 and P1t)
#define TROWS 12            // tile v-rows: v = lo-2 .. lo+9
#define TSZ   (P0C * TROWS) // 3132 uint4 = 50,112 B -> 3 blocks/CU
#define OUTN  (8 * NA * 256)

typedef _Float16 h2  __attribute__((ext_vector_type(2)));
typedef _Float16 h8  __attribute__((ext_vector_type(8)));
typedef __fp16   hf2 __attribute__((ext_vector_type(2)));

__device__ __forceinline__ h2 pkrtz(float a, float b) {
    hf2 t = __builtin_amdgcn_cvt_pkrtz(a, b);
    return __builtin_bit_cast(h2, t);
}
__device__ __forceinline__ float fdot2f(h2 a, h2 b, float c) {
#if __has_builtin(__builtin_amdgcn_fdot2)
    return __builtin_amdgcn_fdot2(__builtin_bit_cast(hf2, a),
                                  __builtin_bit_cast(hf2, b), c, false);
#else
    return c + (float)a.x * (float)b.x + (float)a.y * (float)b.y;
#endif
}
__device__ __forceinline__ float imc(const float* im, int y, int x) {
    return ((unsigned)y < 256u && (unsigned)x < 256u) ? im[(y << 8) + x] : 0.0f;
}

// Batch-packed bordered texels (4 batches per 16 B uint4), BOTH arrays now
// have identical [273 rows (pv=v+4)][261 cols (u+2)] geometry so the radon
// tile is always [12 v-rows][261 u] with u minor (conflict-free gathers):
//  P0 [bg][pv][j] : 4 x h2( im_b(v,u),  im_b(v+1,u) ),  v=pv-4, u=j-2
//  P1t[bg][pv][j] : 4 x h2( im_b(u,v),  im_b(u,v+1) ),  v=pv-4, u=j-2
// One thread builds one full uint4 (coalesced 16B store). Also zeroes `out`
// and builds the per-angle (cos, sin) table.
__global__ __launch_bounds__(256) void prep_kernel(
    const float* __restrict__ img, uint4* __restrict__ P0,
    uint4* __restrict__ P1, float* __restrict__ out, float* __restrict__ tab)
{
    const int tid = threadIdx.x;
    const int row = blockIdx.x;            // 0..P0R-1
    const int mb  = blockIdx.y;            // 0,1: P0 bg ; 2,3: P1t bg

    if (mb == 0) {                         // zero the atomic output
        for (int i = row * 256 + tid; i < OUTN; i += P0R * 256) out[i] = 0.0f;
    }
    if (mb == 1 && row == 0 && tid < NA) { // angle table
        const float theta = (float)tid * ((float)M_PI / (float)NA);
        tab[tid]      = cosf(theta);
        tab[tid + NA] = sinf(theta);
    }

    const int bg = mb & 1;
    const float* im0 = img + ((size_t)(bg * 4) << 16);
    const int v = row - 4;

    if (mb < 2) {
        uint4* dst = P0 + (size_t)(bg * P0R + row) * P0C;
        for (int j = tid; j < P0C; j += 256) {
            const int u = j - 2;
            h8 t;
            t[0] = (_Float16)imc(im0,             v, u); t[1] = (_Float16)imc(im0,             v + 1, u);
            t[2] = (_Float16)imc(im0 + (1 << 16), v, u); t[3] = (_Float16)imc(im0 + (1 << 16), v + 1, u);
            t[4] = (_Float16)imc(im0 + (2 << 16), v, u); t[5] = (_Float16)imc(im0 + (2 << 16), v + 1, u);
            t[6] = (_Float16)imc(im0 + (3 << 16), v, u); t[7] = (_Float16)imc(im0 + (3 << 16), v + 1, u);
            dst[j] = __builtin_bit_cast(uint4, t);
        }
    } else {
        uint4* dst = P1 + (size_t)(bg * P0R + row) * P0C;
        for (int j = tid; j < P0C; j += 256) {
            const int u = j - 2;
            h8 t;
            t[0] = (_Float16)imc(im0,             u, v); t[1] = (_Float16)imc(im0,             u, v + 1);
            t[2] = (_Float16)imc(im0 + (1 << 16), u, v); t[3] = (_Float16)imc(im0 + (1 << 16), u, v + 1);
            t[4] = (_Float16)imc(im0 + (2 << 16), u, v); t[5] = (_Float16)imc(im0 + (2 << 16), u, v + 1);
            t[6] = (_Float16)imc(im0 + (3 << 16), u, v); t[7] = (_Float16)imc(im0 + (3 << 16), u, v + 1);
            dst[j] = __builtin_bit_cast(uint4, t);
        }
    }
}

// One sample: gather packed texel pair (u and u+1 -> idx, idx+1), bilinear
// for 4 batches, accumulate. Mode-independent: tile is always [12][261].
#define SAMPLE(JV, UV, VPV, A0, A1, A2, A3)                                   \
    {                                                                         \
        const float ucl = fminf(fmaxf((UV), -1.5f), 257.5f);                  \
        const float uf = floorf(ucl);                                         \
        const float wu = ucl - uf;                                            \
        const float vf = floorf(VPV);                                         \
        const float wv = (VPV) - vf;                                          \
        const float vfc = fminf(fmaxf(vf, -2.0f), 9.0f);                      \
        const int idx = (int)fmaf(vfc, 261.0f, uf) + 524;                     \
        const h8 A8 = __builtin_bit_cast(h8, s_tile[idx]);                    \
        const h8 B8 = __builtin_bit_cast(h8, s_tile[idx + 1]);                \
        const h2 wu2 = pkrtz(wu, wu);                                         \
        const h8 wu8 = __builtin_shufflevector(wu2, wu2, 0,1,0,1,0,1,0,1);    \
        const h8 tb8 = (B8 - A8) * wu8 + A8;                                  \
        h2 wv2 = pkrtz(1.0f - wv, wv);                                        \
        wv2 = ((unsigned)(JV) < span) ? wv2 : hz;                             \
        A0 = fdot2f(__builtin_shufflevector(tb8, tb8, 0, 1), wv2, A0);        \
        A1 = fdot2f(__builtin_shufflevector(tb8, tb8, 2, 3), wv2, A1);        \
        A2 = fdot2f(__builtin_shufflevector(tb8, tb8, 4, 5), wv2, A2);        \
        A3 = fdot2f(__builtin_shufflevector(tb8, tb8, 6, 7), wv2, A3);        \
    }

template<bool MODEX>
__device__ __forceinline__ void radon_body(
    const uint4* __restrict__ Pbase,   // batch-group base of P0 (Y) / P1t (X)
    float* __restrict__ out, const float* __restrict__ tab,
    uint4* s_tile, int tid, int b0, int p, int gi)
{
    const int lo = -2 + p * HB;

    // ---- stage band tile: rows pv = lo+2 .. lo+13, linear copy (both modes)
    {
        const uint4* src = Pbase + (size_t)(lo + 2) * P0C;
        for (int i = tid; i < TSZ; i += 256) s_tile[i] = src[i];
    }
    __syncthreads();

    const float detf = (float)tid - 127.5f;
    const float lof = (float)lo;
    const h2 hz = {};

    for (int g = 0; g < 7; ++g) {
        const int ai = gi * 7 + g;
        int a;
        if (MODEX) { if (ai >= 89) break; a = 46 + ai; }   // 46..134
        else       { a = (ai <= 45) ? ai : 89 + ai; }      // 0..45, 135..179

        const float c = tab[a];            // uniform -> scalar load
        const float s = tab[a + NA];

        const float xc = 127.5f + detf * c + 127.5f * s;   // x at k=0
        const float yc = 127.5f + detf * s - 127.5f * c;   // y at k=0

        const float ucst = MODEX ? yc : xc;
        const float vcst = MODEX ? xc : yc;
        const float du   = MODEX ? c  : -s;
        const float dv   = MODEX ? -s : c;

        // band-crossing k-window; identical float exprs on shared boundaries
        // of adjacent bands -> exact partition of k-space (no dup/miss)
        const float inv = 1.0f / dv;
        const float f1 = (lof - vcst) * inv;
        const float f2 = (lof + (float)HB - vcst) * inv;
        const float fmn = fminf(f1, f2);
        const float fmx = fmaxf(f1, f2);
        int kmin, kend;
        if (dv > 0.0f) { kmin = (int)ceilf(fmn);      kend = (int)ceilf(fmx); }
        else           { kmin = (int)floorf(fmn) + 1; kend = (int)floorf(fmx) + 1; }

        const int len = kend - kmin;
        const int jlo = max(0, -kmin);
        const int jhi = min(len, 256 - kmin);
        const int spani = max(0, jhi - jlo);
        if (!__any(spani > 0)) continue;
        const unsigned span = (unsigned)spani;

        const int kstart = kmin + jlo;
        const int Lmax = (int)((float)HB * fabsf(inv)) + 2;  // angle-uniform

        float u  = fmaf((float)kstart, du, ucst);
        float vp = fmaf((float)kstart, dv, vcst - lof);      // v relative to lo
        const float du2 = du + du, dv2 = dv + dv;

        float a0 = 0.f, a1 = 0.f, a2 = 0.f, a3 = 0.f;        // phase A accs
        float b0a = 0.f, b1a = 0.f, b2a = 0.f, b3a = 0.f;    // phase B accs

        int j = 0;
        for (; j + 1 < Lmax; j += 2) {                       // 2 indep chains
            SAMPLE(j,     u,      vp,      a0, a1, a2, a3);
            SAMPLE(j + 1, u + du, vp + dv, b0a, b1a, b2a, b3a);
            u += du2; vp += dv2;
        }
        if (j < Lmax) SAMPLE(j, u, vp, a0, a1, a2, a3);

        if (spani > 0) {
            float* o = &out[((b0 * NA + a) << 8) + tid];
            atomicAdd(o,                 a0 + b0a);
            atomicAdd(o + (NA << 8),     a1 + b1a);
            atomicAdd(o + 2 * (NA << 8), a2 + b2a);
            atomicAdd(o + 3 * (NA << 8), a3 + b3a);
        }
    }
}

// grid = (2 batch-groups, KB bands, 26 angle-groups)
__global__ __launch_bounds__(256, 3) void radon_kernel(
    const uint4* __restrict__ P0, const uint4* __restrict__ P1,
    float* __restrict__ out, const float* __restrict__ tab)
{
    __shared__ uint4 s_tile[TSZ];                  // 50,112 B -> 3 blocks/CU
    const int tid = threadIdx.x;
    const int bg  = blockIdx.x;
    const int p   = blockIdx.y;
    const int gid = blockIdx.z;                    // 0..25
    const int b0  = bg * 4;
    if (gid < 13)
        radon_body<false>(P0 + (size_t)bg * P0R * P0C, out, tab, s_tile, tid, b0, p, gid);
    else
        radon_body<true>(P1 + (size_t)bg * P0R * P0C, out, tab, s_tile, tid, b0, p, gid - 13);
}

extern "C" void kernel_launch(void* const* d_in, const int* in_sizes, int n_in,
                              void* d_out, int out_size, void* d_ws, size_t ws_size,
                              hipStream_t stream) {
    const float* img = (const float*)d_in[0];
    float* out = (float*)d_out;

    uint4* P0 = (uint4*)d_ws;                       // 2*273*261*16 B
    uint4* P1 = P0 + (size_t)2 * P0R * P0C;         // 2*273*261*16 B
    float* tab = (float*)(P1 + (size_t)2 * P0R * P0C);  // 360 floats

    prep_kernel<<<dim3(P0R, 4), 256, 0, stream>>>(img, P0, P1, out, tab);
    radon_kernel<<<dim3(2, KB, 26), 256, 0, stream>>>(P0, P1, out, tab);
}

// Round 3
// 106.168 us; speedup vs baseline: 1.0509x; 1.0509x over previous
//
#include <hip/hip_runtime.h>
#include <math.h>

#define NA    180
#define HB    9             // band height in v
#define KB    29            // bands cover v in [-2, 259)
#define PC    262           // row stride in texels (cols 0..260 valid, 261 = pad)
#define PR    264           // rows: pv = v+3, v = -3..260
#define TROWS 12            // tile v-rows: v = lo-1 .. lo+10
#define TSZ   (PC * TROWS)  // 3144 uint2 = 25,152 B -> 6 blocks/CU
#define TSZ4  (TSZ / 2)     // staged as uint4
#define OUTN  (8 * NA * 256)

typedef _Float16 h2  __attribute__((ext_vector_type(2)));
typedef _Float16 h4  __attribute__((ext_vector_type(4)));
typedef __fp16   hf2 __attribute__((ext_vector_type(2)));

__device__ __forceinline__ h2 pkrtz(float a, float b) {
    hf2 t = __builtin_amdgcn_cvt_pkrtz(a, b);
    return __builtin_bit_cast(h2, t);
}
__device__ __forceinline__ float fdot2f(h2 a, h2 b, float c) {
#if __has_builtin(__builtin_amdgcn_fdot2)
    return __builtin_amdgcn_fdot2(__builtin_bit_cast(hf2, a),
                                  __builtin_bit_cast(hf2, b), c, false);
#else
    return c + (float)a.x * (float)b.x + (float)a.y * (float)b.y;
#endif
}
__device__ __forceinline__ float imc(const float* im, int y, int x) {
    return ((unsigned)y < 256u && (unsigned)x < 256u) ? im[(y << 8) + x] : 0.0f;
}

// Non-duplicated batch-packed texels (4 batches per 8 B uint2), identical
// [264 rows (pv=v+3)][262 cols (u+2, col 261 = zero pad)] geometry for both:
//  P0 [bg][pv][j] : 4 x f16 im_b(v,u),  v=pv-3, u=j-2   (Y-mode)
//  P1t[bg][pv][j] : 4 x f16 im_b(u,v),  v=pv-3, u=j-2   (X-mode, transposed)
// One thread builds one 8 B entry (coalesced). Also zeroes `out` and builds
// the per-angle (cos, sin) table.
__global__ __launch_bounds__(256) void prep_kernel(
    const float* __restrict__ img, uint2* __restrict__ P0,
    uint2* __restrict__ P1, float* __restrict__ out, float* __restrict__ tab)
{
    const int tid = threadIdx.x;
    const int row = blockIdx.x;            // 0..PR-1
    const int mb  = blockIdx.y;            // 0,1: P0 bg ; 2,3: P1t bg

    if (mb == 0) {                         // zero the atomic output
        for (int i = row * 256 + tid; i < OUTN; i += PR * 256) out[i] = 0.0f;
    }
    if (mb == 1 && row == 0 && tid < NA) { // angle table
        const float theta = (float)tid * ((float)M_PI / (float)NA);
        tab[tid]      = cosf(theta);
        tab[tid + NA] = sinf(theta);
    }

    const int bg = mb & 1;
    const float* im0 = img + ((size_t)(bg * 4) << 16);
    const int v = row - 3;

    if (mb < 2) {
        uint2* dst = P0 + (size_t)(bg * PR + row) * PC;
        for (int j = tid; j < PC; j += 256) {
            const int u = j - 2;
            h4 t = {};
            if (j < 261) {
                t[0] = (_Float16)imc(im0,             v, u);
                t[1] = (_Float16)imc(im0 + (1 << 16), v, u);
                t[2] = (_Float16)imc(im0 + (2 << 16), v, u);
                t[3] = (_Float16)imc(im0 + (3 << 16), v, u);
            }
            dst[j] = __builtin_bit_cast(uint2, t);
        }
    } else {
        uint2* dst = P1 + (size_t)(bg * PR + row) * PC;
        for (int j = tid; j < PC; j += 256) {
            const int u = j - 2;
            h4 t = {};
            if (j < 261) {
                t[0] = (_Float16)imc(im0,             u, v);
                t[1] = (_Float16)imc(im0 + (1 << 16), u, v);
                t[2] = (_Float16)imc(im0 + (2 << 16), u, v);
                t[3] = (_Float16)imc(im0 + (3 << 16), u, v);
            }
            dst[j] = __builtin_bit_cast(uint2, t);
        }
    }
}

// One sample: read 4 texels (rows v,v+1 x cols u,u+1; row-pairs merge into
// ds_read2_b64), v-lerp in packed f16, u-lerp via fdot2 into f32 accs.
#define SAMPLE(JV, UV, VPV, A0, A1, A2, A3)                                   \
    {                                                                         \
        const float ucl = fminf(fmaxf((UV), -1.5f), 257.5f);                  \
        const float uf = floorf(ucl);                                         \
        const float wu = ucl - uf;                                            \
        const float vf = floorf(VPV);                                         \
        const float wv = (VPV) - vf;                                          \
        const float vfc = fminf(fmaxf(vf, -1.0f), 9.0f);                      \
        const int idx = (int)fmaf(vfc, (float)PC, uf) + (PC + 2);             \
        const h4 r00 = __builtin_bit_cast(h4, s_tile[idx]);                   \
        const h4 r01 = __builtin_bit_cast(h4, s_tile[idx + 1]);               \
        const h4 r10 = __builtin_bit_cast(h4, s_tile[idx + PC]);              \
        const h4 r11 = __builtin_bit_cast(h4, s_tile[idx + PC + 1]);          \
        const h2 wv2 = pkrtz(wv, wv);                                         \
        const h4 wv4 = __builtin_shufflevector(wv2, wv2, 0, 1, 0, 1);         \
        const h4 V0 = (r10 - r00) * wv4 + r00;                                \
        const h4 V1 = (r11 - r01) * wv4 + r01;                                \
        h2 wu2 = pkrtz(1.0f - wu, wu);                                        \
        wu2 = ((unsigned)(JV) < span) ? wu2 : hz;                             \
        A0 = fdot2f(__builtin_shufflevector(V0, V1, 0, 4), wu2, A0);          \
        A1 = fdot2f(__builtin_shufflevector(V0, V1, 1, 5), wu2, A1);          \
        A2 = fdot2f(__builtin_shufflevector(V0, V1, 2, 6), wu2, A2);          \
        A3 = fdot2f(__builtin_shufflevector(V0, V1, 3, 7), wu2, A3);          \
    }

template<bool MODEX>
__device__ __forceinline__ void radon_body(
    const uint2* __restrict__ Pbase,   // batch-group base of P0 (Y) / P1t (X)
    float* __restrict__ out, const float* __restrict__ tab,
    uint2* s_tile, int tid, int b0, int p, int gi)
{
    const int lo = -2 + p * HB;

    // ---- stage band tile: rows pv = lo+2 .. lo+13 (v = lo-1..lo+10)
    // (lo+2) = 9p and PC*8 = 2096 B are both 16B-aligned -> uint4 copy
    {
        const uint4* src = (const uint4*)(Pbase + (size_t)(lo + 2) * PC);
        uint4* dst = (uint4*)s_tile;
        for (int i = tid; i < TSZ4; i += 256) dst[i] = src[i];
    }
    __syncthreads();

    const float detf = (float)tid - 127.5f;
    const float lof = (float)lo;
    const h2 hz = {};

    for (int g = 0; g < 7; ++g) {
        const int ai = gi * 7 + g;
        int a;
        if (MODEX) { if (ai >= 89) break; a = 46 + ai; }   // 46..134
        else       { a = (ai <= 45) ? ai : 89 + ai; }      // 0..45, 135..179

        const float c = tab[a];            // uniform -> scalar load
        const float s = tab[a + NA];

        const float xc = 127.5f + detf * c + 127.5f * s;   // x at k=0
        const float yc = 127.5f + detf * s - 127.5f * c;   // y at k=0

        const float ucst = MODEX ? yc : xc;
        const float vcst = MODEX ? xc : yc;
        const float du   = MODEX ? c  : -s;
        const float dv   = MODEX ? -s : c;

        // band-crossing k-window; identical float exprs on shared boundaries
        // of adjacent bands -> exact partition of k-space (no dup/miss)
        const float inv = 1.0f / dv;
        const float f1 = (lof - vcst) * inv;
        const float f2 = (lof + (float)HB - vcst) * inv;
        const float fmn = fminf(f1, f2);
        const float fmx = fmaxf(f1, f2);
        int kmin, kend;
        if (dv > 0.0f) { kmin = (int)ceilf(fmn);      kend = (int)ceilf(fmx); }
        else           { kmin = (int)floorf(fmn) + 1; kend = (int)floorf(fmx) + 1; }

        const int len = kend - kmin;
        const int jlo = max(0, -kmin);
        const int jhi = min(len, 256 - kmin);
        const int spani = max(0, jhi - jlo);
        if (!__any(spani > 0)) continue;
        const unsigned span = (unsigned)spani;

        const int kstart = kmin + jlo;
        const int Lmax = (int)((float)HB * fabsf(inv)) + 2;  // angle-uniform

        float u  = fmaf((float)kstart, du, ucst);
        float vp = fmaf((float)kstart, dv, vcst - lof);      // v relative to lo
        const float du2 = du + du, dv2 = dv + dv;

        float a0 = 0.f, a1 = 0.f, a2 = 0.f, a3 = 0.f;        // phase A accs
        float b0a = 0.f, b1a = 0.f, b2a = 0.f, b3a = 0.f;    // phase B accs

        int j = 0;
        for (; j + 1 < Lmax; j += 2) {                       // 2 indep chains
            SAMPLE(j,     u,      vp,      a0, a1, a2, a3);
            SAMPLE(j + 1, u + du, vp + dv, b0a, b1a, b2a, b3a);
            u += du2; vp += dv2;
        }
        if (j < Lmax) SAMPLE(j, u, vp, a0, a1, a2, a3);

        if (spani > 0) {
            float* o = &out[((b0 * NA + a) << 8) + tid];
            atomicAdd(o,                 a0 + b0a);
            atomicAdd(o + (NA << 8),     a1 + b1a);
            atomicAdd(o + 2 * (NA << 8), a2 + b2a);
            atomicAdd(o + 3 * (NA << 8), a3 + b3a);
        }
    }
}

// grid = (2 batch-groups, KB bands, 26 angle-groups)
__global__ __launch_bounds__(256, 6) void radon_kernel(
    const uint2* __restrict__ P0, const uint2* __restrict__ P1,
    float* __restrict__ out, const float* __restrict__ tab)
{
    __shared__ uint2 s_tile[TSZ];                  // 25,152 B -> 6 blocks/CU
    const int tid = threadIdx.x;
    const int bg  = blockIdx.x;
    const int p   = blockIdx.y;
    const int gid = blockIdx.z;                    // 0..25
    const int b0  = bg * 4;
    if (gid < 13)
        radon_body<false>(P0 + (size_t)bg * PR * PC, out, tab, s_tile, tid, b0, p, gid);
    else
        radon_body<true>(P1 + (size_t)bg * PR * PC, out, tab, s_tile, tid, b0, p, gid - 13);
}

extern "C" void kernel_launch(void* const* d_in, const int* in_sizes, int n_in,
                              void* d_out, int out_size, void* d_ws, size_t ws_size,
                              hipStream_t stream) {
    const float* img = (const float*)d_in[0];
    float* out = (float*)d_out;

    uint2* P0 = (uint2*)d_ws;                       // 2*264*262*8 B
    uint2* P1 = P0 + (size_t)2 * PR * PC;           // 2*264*262*8 B
    float* tab = (float*)(P1 + (size_t)2 * PR * PC);    // 360 floats

    prep_kernel<<<dim3(PR, 4), 256, 0, stream>>>(img, P0, P1, out, tab);
    radon_kernel<<<dim3(2, KB, 26), 256, 0, stream>>>(P0, P1, out, tab);
}

// Round 4
// 100.420 us; speedup vs baseline: 1.1110x; 1.0572x over previous
//
#include <hip/hip_runtime.h>
#include <math.h>

#define NA    180
#define HB    9             // band height in v
#define KB    29            // bands cover v in [-2, 259)
#define PC    262           // row stride in texels (cols 0..260 valid, 261 = pad)
#define PR    264           // rows: pv = v+3, v = -3..260
#define TROWS 12            // tile v-rows: v = lo-1 .. lo+10
#define TSZ   (PC * TROWS)  // 3144 uint2 = 25,152 B -> 6 blocks/CU
#define TSZ4  (TSZ / 2)     // staged as uint4
#define OUTN  (8 * NA * 256)
#define APG   4             // angles per block (fine-grained for tail balance)
#define NG    23            // ceil(91/APG) groups per mode

typedef _Float16 h2  __attribute__((ext_vector_type(2)));
typedef _Float16 h4  __attribute__((ext_vector_type(4)));
typedef __fp16   hf2 __attribute__((ext_vector_type(2)));

__device__ __forceinline__ h2 pkrtz(float a, float b) {
    hf2 t = __builtin_amdgcn_cvt_pkrtz(a, b);
    return __builtin_bit_cast(h2, t);
}
__device__ __forceinline__ float fdot2f(h2 a, h2 b, float c) {
#if __has_builtin(__builtin_amdgcn_fdot2)
    return __builtin_amdgcn_fdot2(__builtin_bit_cast(hf2, a),
                                  __builtin_bit_cast(hf2, b), c, false);
#else
    return c + (float)a.x * (float)b.x + (float)a.y * (float)b.y;
#endif
}
__device__ __forceinline__ float imc(const float* im, int y, int x) {
    return ((unsigned)y < 256u && (unsigned)x < 256u) ? im[(y << 8) + x] : 0.0f;
}

// Non-duplicated batch-packed texels (4 batches per 8 B uint2), identical
// [264 rows (pv=v+3)][262 cols (u+2, col 261 = zero pad)] geometry for both:
//  P0 [bg][pv][j] : 4 x f16 im_b(v,u),  v=pv-3, u=j-2   (Y-mode)
//  P1t[bg][pv][j] : 4 x f16 im_b(u,v),  v=pv-3, u=j-2   (X-mode, transposed)
__global__ __launch_bounds__(256) void prep_kernel(
    const float* __restrict__ img, uint2* __restrict__ P0,
    uint2* __restrict__ P1, float* __restrict__ out, float* __restrict__ tab)
{
    const int tid = threadIdx.x;
    const int row = blockIdx.x;            // 0..PR-1
    const int mb  = blockIdx.y;            // 0,1: P0 bg ; 2,3: P1t bg

    if (mb == 0) {                         // zero the atomic output
        for (int i = row * 256 + tid; i < OUTN; i += PR * 256) out[i] = 0.0f;
    }
    if (mb == 1 && row == 0 && tid < NA) { // angle table
        const float theta = (float)tid * ((float)M_PI / (float)NA);
        tab[tid]      = cosf(theta);
        tab[tid + NA] = sinf(theta);
    }

    const int bg = mb & 1;
    const float* im0 = img + ((size_t)(bg * 4) << 16);
    const int v = row - 3;

    if (mb < 2) {
        uint2* dst = P0 + (size_t)(bg * PR + row) * PC;
        for (int j = tid; j < PC; j += 256) {
            const int u = j - 2;
            h4 t = {};
            if (j < 261) {
                t[0] = (_Float16)imc(im0,             v, u);
                t[1] = (_Float16)imc(im0 + (1 << 16), v, u);
                t[2] = (_Float16)imc(im0 + (2 << 16), v, u);
                t[3] = (_Float16)imc(im0 + (3 << 16), v, u);
            }
            dst[j] = __builtin_bit_cast(uint2, t);
        }
    } else {
        uint2* dst = P1 + (size_t)(bg * PR + row) * PC;
        for (int j = tid; j < PC; j += 256) {
            const int u = j - 2;
            h4 t = {};
            if (j < 261) {
                t[0] = (_Float16)imc(im0,             u, v);
                t[1] = (_Float16)imc(im0 + (1 << 16), u, v);
                t[2] = (_Float16)imc(im0 + (2 << 16), u, v);
                t[3] = (_Float16)imc(im0 + (3 << 16), u, v);
            }
            dst[j] = __builtin_bit_cast(uint2, t);
        }
    }
}

// One sample: read 4 texels (rows v,v+1 x cols u,u+1), v-lerp in packed f16,
// u-lerp via fdot2 into f32 accs.
#define SAMPLE(JV, UV, VPV, A0, A1, A2, A3)                                   \
    {                                                                         \
        const float ucl = fminf(fmaxf((UV), -1.5f), 257.5f);                  \
        const float uf = floorf(ucl);                                         \
        const float wu = ucl - uf;                                            \
        const float vf = floorf(VPV);                                         \
        const float wv = (VPV) - vf;                                          \
        const float vfc = fminf(fmaxf(vf, -1.0f), 9.0f);                      \
        const int idx = (int)fmaf(vfc, (float)PC, uf) + (PC + 2);             \
        const h4 r00 = __builtin_bit_cast(h4, s_tile[idx]);                   \
        const h4 r01 = __builtin_bit_cast(h4, s_tile[idx + 1]);               \
        const h4 r10 = __builtin_bit_cast(h4, s_tile[idx + PC]);              \
        const h4 r11 = __builtin_bit_cast(h4, s_tile[idx + PC + 1]);          \
        const h2 wv2 = pkrtz(wv, wv);                                         \
        const h4 wv4 = __builtin_shufflevector(wv2, wv2, 0, 1, 0, 1);         \
        const h4 V0 = (r10 - r00) * wv4 + r00;                                \
        const h4 V1 = (r11 - r01) * wv4 + r01;                                \
        h2 wu2 = pkrtz(1.0f - wu, wu);                                        \
        wu2 = ((unsigned)(JV) < span) ? wu2 : hz;                             \
        A0 = fdot2f(__builtin_shufflevector(V0, V1, 0, 4), wu2, A0);          \
        A1 = fdot2f(__builtin_shufflevector(V0, V1, 1, 5), wu2, A1);         \
        A2 = fdot2f(__builtin_shufflevector(V0, V1, 2, 6), wu2, A2);          \
        A3 = fdot2f(__builtin_shufflevector(V0, V1, 3, 7), wu2, A3);          \
    }

template<bool MODEX>
__device__ __forceinline__ void radon_body(
    const uint2* __restrict__ Pbase,   // batch-group base of P0 (Y) / P1t (X)
    float* __restrict__ out, const float* __restrict__ tab,
    uint2* s_tile, int tid, int b0, int p, int gi)
{
    const int lo = -2 + p * HB;

    // ---- stage band tile: rows pv = lo+2 .. lo+13 (v = lo-1..lo+10)
    {
        const uint4* src = (const uint4*)(Pbase + (size_t)(lo + 2) * PC);
        uint4* dst = (uint4*)s_tile;
        for (int i = tid; i < TSZ4; i += 256) dst[i] = src[i];
    }
    __syncthreads();

    const float detf = (float)tid - 127.5f;
    const float lof = (float)lo;
    const h2 hz = {};

    for (int g = 0; g < APG; ++g) {
        const int ai = gi * APG + g;
        int a;
        if (MODEX) { if (ai >= 89) break; a = 46 + ai; }   // 46..134
        else       { if (ai >= 91) break; a = (ai <= 45) ? ai : 89 + ai; }

        const float c = tab[a];            // uniform -> scalar load
        const float s = tab[a + NA];

        const float xc = 127.5f + detf * c + 127.5f * s;   // x at k=0
        const float yc = 127.5f + detf * s - 127.5f * c;   // y at k=0

        const float ucst = MODEX ? yc : xc;
        const float vcst = MODEX ? xc : yc;
        const float du   = MODEX ? c  : -s;
        const float dv   = MODEX ? -s : c;

        // band-crossing k-window; identical float exprs on shared boundaries
        // of adjacent bands -> exact partition of k-space (no dup/miss)
        const float inv = 1.0f / dv;
        const float f1 = (lof - vcst) * inv;
        const float f2 = (lof + (float)HB - vcst) * inv;
        const float fmn = fminf(f1, f2);
        const float fmx = fmaxf(f1, f2);
        int kmin, kend;
        if (dv > 0.0f) { kmin = (int)ceilf(fmn);      kend = (int)ceilf(fmx); }
        else           { kmin = (int)floorf(fmn) + 1; kend = (int)floorf(fmx) + 1; }

        const int len = kend - kmin;
        const int jlo = max(0, -kmin);
        const int jhi = min(len, 256 - kmin);
        const int spani = max(0, jhi - jlo);
        if (!__any(spani > 0)) continue;
        const unsigned span = (unsigned)spani;

        const int kstart = kmin + jlo;
        const int Lmax = (int)((float)HB * fabsf(inv)) + 2;  // angle-uniform

        float u  = fmaf((float)kstart, du, ucst);
        float vp = fmaf((float)kstart, dv, vcst - lof);      // v relative to lo
        const float du2 = du + du, dv2 = dv + dv;
        const float du3 = du2 + du, dv3 = dv2 + dv;
        const float du4 = du2 + du2, dv4 = dv2 + dv2;

        float a0 = 0.f, a1 = 0.f, a2 = 0.f, a3 = 0.f;       // 4 indep chains
        float e0 = 0.f, e1 = 0.f, e2 = 0.f, e3 = 0.f;
        float c0 = 0.f, c1 = 0.f, c2 = 0.f, c3 = 0.f;
        float d0 = 0.f, d1 = 0.f, d2 = 0.f, d3 = 0.f;

        int j = 0;
        for (; j + 3 < Lmax; j += 4) {
            SAMPLE(j,     u,        vp,        a0, a1, a2, a3);
            SAMPLE(j + 1, u + du,   vp + dv,   e0, e1, e2, e3);
            SAMPLE(j + 2, u + du2,  vp + dv2,  c0, c1, c2, c3);
            SAMPLE(j + 3, u + du3,  vp + dv3,  d0, d1, d2, d3);
            u += du4; vp += dv4;
        }
        for (; j + 1 < Lmax; j += 2) {
            SAMPLE(j,     u,      vp,      a0, a1, a2, a3);
            SAMPLE(j + 1, u + du, vp + dv, e0, e1, e2, e3);
            u += du2; vp += dv2;
        }
        if (j < Lmax) SAMPLE(j, u, vp, a0, a1, a2, a3);

        if (spani > 0) {
            float* o = &out[((b0 * NA + a) << 8) + tid];
            atomicAdd(o,                 (a0 + c0) + (e0 + d0));
            atomicAdd(o + (NA << 8),     (a1 + c1) + (e1 + d1));
            atomicAdd(o + 2 * (NA << 8), (a2 + c2) + (e2 + d2));
            atomicAdd(o + 3 * (NA << 8), (a3 + c3) + (e3 + d3));
        }
    }
}

// grid = (2 batch-groups, KB bands, 2*NG angle-groups)
__global__ __launch_bounds__(256, 6) void radon_kernel(
    const uint2* __restrict__ P0, const uint2* __restrict__ P1,
    float* __restrict__ out, const float* __restrict__ tab)
{
    __shared__ uint2 s_tile[TSZ];                  // 25,152 B -> 6 blocks/CU
    const int tid = threadIdx.x;
    const int bg  = blockIdx.x;
    const int p   = blockIdx.y;
    const int gid = blockIdx.z;                    // 0..2*NG-1
    const int b0  = bg * 4;
    if (gid < NG)
        radon_body<false>(P0 + (size_t)bg * PR * PC, out, tab, s_tile, tid, b0, p, gid);
    else
        radon_body<true>(P1 + (size_t)bg * PR * PC, out, tab, s_tile, tid, b0, p, gid - NG);
}

extern "C" void kernel_launch(void* const* d_in, const int* in_sizes, int n_in,
                              void* d_out, int out_size, void* d_ws, size_t ws_size,
                              hipStream_t stream) {
    const float* img = (const float*)d_in[0];
    float* out = (float*)d_out;

    uint2* P0 = (uint2*)d_ws;                       // 2*264*262*8 B
    uint2* P1 = P0 + (size_t)2 * PR * PC;           // 2*264*262*8 B
    float* tab = (float*)(P1 + (size_t)2 * PR * PC);    // 360 floats

    prep_kernel<<<dim3(PR, 4), 256, 0, stream>>>(img, P0, P1, out, tab);
    radon_kernel<<<dim3(2, KB, 2 * NG), 256, 0, stream>>>(P0, P1, out, tab);
}